// Round 14
// baseline (288.467 us; speedup 1.0000x reference)
//
#include <hip/hip_runtime.h>
#include <hip/hip_bf16.h>
#include <stdint.h>

#define S_LEN 2048
#define NHEADS 16
#define HDIM 128
#define H_TOT 2048
#define BATCH 2
#define M_TOK 4096   // B*S
#define KDIM 2048

typedef __attribute__((ext_vector_type(8))) short bf16x8;
typedef __attribute__((ext_vector_type(4))) float f32x4;
typedef __attribute__((ext_vector_type(16))) float f32x16;

__device__ inline ushort bf16rn(float f) {
  union { float f; uint32_t u; } x; x.f = f;
  uint32_t r = x.u + 0x7FFF + ((x.u >> 16) & 1);
  return (ushort)(r >> 16);
}

// ---------------- f32 -> bf16 conversion ----------------
__global__ __launch_bounds__(256) void cvt_bf16_kernel(const float* __restrict__ in,
                                                       ushort* __restrict__ out, int n4) {
  int i = blockIdx.x * blockDim.x + threadIdx.x;
  int stride = gridDim.x * blockDim.x;
  for (; i < n4; i += stride) {
    float4 v = reinterpret_cast<const float4*>(in)[i];
    ushort4 o;
    o.x = bf16rn(v.x); o.y = bf16rn(v.y); o.z = bf16rn(v.z); o.w = bf16rn(v.w);
    reinterpret_cast<ushort4*>(out)[i] = o;
  }
}

__global__ __launch_bounds__(256) void cvt4_bf16_kernel(const float* __restrict__ w0,
                                                        const float* __restrict__ w1,
                                                        const float* __restrict__ w2,
                                                        const float* __restrict__ w3,
                                                        ushort* __restrict__ o0,
                                                        ushort* __restrict__ o1,
                                                        ushort* __restrict__ o2,
                                                        ushort* __restrict__ o3) {
  const int N4 = KDIM * KDIM / 4;  // 1<<20
  int i = blockIdx.x * blockDim.x + threadIdx.x;
  int stride = gridDim.x * blockDim.x;
  for (; i < 4 * N4; i += stride) {
    int seg = i >> 20, off = i & (N4 - 1);
    const float* in = (seg == 0) ? w0 : (seg == 1) ? w1 : (seg == 2) ? w2 : w3;
    ushort* out = (seg == 0) ? o0 : (seg == 1) ? o1 : (seg == 2) ? o2 : o3;
    float4 v = reinterpret_cast<const float4*>(in)[off];
    ushort4 o;
    o.x = bf16rn(v.x); o.y = bf16rn(v.y); o.z = bf16rn(v.z); o.w = bf16rn(v.w);
    reinterpret_cast<ushort4*>(out)[off] = o;
  }
}

// ---------------- pipelined NT GEMM (round-6/13 best: 127.5us QKV) ----------------
template<int MODE, int NBX>
__global__ __launch_bounds__(512) void gemm2(const ushort* __restrict__ A,
                                             const ushort* __restrict__ Bw,
                                             void* __restrict__ C0,
                                             void* __restrict__ C1,
                                             void* __restrict__ C2,
                                             const float* __restrict__ bias,
                                             float scale) {
  __shared__ __attribute__((aligned(16))) char lds[3 * 49152];  // [buf][A:16KB | B:32KB]
  const int K = KDIM;
  const int NKT = K / 64;  // 32
  int tid = threadIdx.x;
  int wave = tid >> 6, lane = tid & 63;
  int lanelo = lane & 15, lanehi = lane >> 4;
  int wr = wave >> 2, wc = wave & 3;  // 2M x 4N waves, 64x64 output each

  int bid = blockIdx.x;
  const int CHX = NBX / 8;
  int ii = bid >> 3;
  int bx = (bid & 7) * CHX + (ii % CHX);
  int by = ii / CHX;
  int bm = by * 128, bn = bx * 256;

  const ushort* srcA[2];
  const ushort* srcB[4];
#pragma unroll
  for (int i = 0; i < 2; i++) {
    int c = i * 512 + tid, row = c >> 3, slot = c & 7;
    srcA[i] = A + (size_t)(bm + row) * K + ((slot ^ (row & 7)) * 8);
  }
#pragma unroll
  for (int i = 0; i < 4; i++) {
    int c = i * 512 + tid, row = c >> 3, slot = c & 7;
    srcB[i] = Bw + (size_t)(bn + row) * K + ((slot ^ (row & 7)) * 8);
  }

#define STAGE(tile, buf)                                                                    \
  {                                                                                         \
    char* dA = lds + (buf) * 49152 + (size_t)tid * 16;                                      \
    char* dB = lds + (buf) * 49152 + 16384 + (size_t)tid * 16;                              \
    _Pragma("unroll") for (int i_ = 0; i_ < 2; i_++)                                        \
      __builtin_amdgcn_global_load_lds(                                                     \
          (const __attribute__((address_space(1))) void*)(srcA[i_] + (tile) * 64),          \
          (__attribute__((address_space(3))) void*)(dA + i_ * 8192), 16, 0, 0);             \
    _Pragma("unroll") for (int i_ = 0; i_ < 4; i_++)                                        \
      __builtin_amdgcn_global_load_lds(                                                     \
          (const __attribute__((address_space(1))) void*)(srcB[i_] + (tile) * 64),          \
          (__attribute__((address_space(3))) void*)(dB + i_ * 8192), 16, 0, 0);             \
  }

  f32x4 acc[4][4];
#pragma unroll
  for (int i = 0; i < 4; i++)
#pragma unroll
    for (int j = 0; j < 4; j++) acc[i][j] = (f32x4){0.f, 0.f, 0.f, 0.f};

  STAGE(0, 0);
  STAGE(1, 1);
  asm volatile("s_waitcnt vmcnt(6)" ::: "memory");
  __builtin_amdgcn_s_barrier();
  __builtin_amdgcn_sched_barrier(0);

  for (int t = 0; t < NKT; t++) {
    STAGE((t + 2) & (NKT - 1), (t + 2) % 3);

    const ushort* bufc = (const ushort*)(lds + (t % 3) * 49152);

    bf16x8 bfr[4][2];
#pragma unroll
    for (int nf = 0; nf < 4; nf++)
#pragma unroll
      for (int kh = 0; kh < 2; kh++) {
        int row = wc * 64 + nf * 16 + lanelo;
        int slot = (kh * 4 + lanehi) ^ (row & 7);
        bfr[nf][kh] = *reinterpret_cast<const bf16x8*>(&bufc[8192 + row * 64 + slot * 8]);
      }

    __builtin_amdgcn_s_setprio(1);
#pragma unroll
    for (int mf = 0; mf < 4; mf++) {
      int row = wr * 64 + mf * 16 + lanelo;
      bf16x8 af[2];
#pragma unroll
      for (int kh = 0; kh < 2; kh++) {
        int slot = (kh * 4 + lanehi) ^ (row & 7);
        af[kh] = *reinterpret_cast<const bf16x8*>(&bufc[row * 64 + slot * 8]);
      }
#pragma unroll
      for (int nf = 0; nf < 4; nf++)
#pragma unroll
        for (int kh = 0; kh < 2; kh++)
          acc[mf][nf] = __builtin_amdgcn_mfma_f32_16x16x32_bf16(af[kh], bfr[nf][kh],
                                                                acc[mf][nf], 0, 0, 0);
    }
    __builtin_amdgcn_s_setprio(0);

    asm volatile("s_waitcnt vmcnt(6)" ::: "memory");
    __builtin_amdgcn_s_barrier();
    __builtin_amdgcn_sched_barrier(0);
  }

  // ---------------- epilogue ----------------
  if (MODE == 2) {
    float* Cf = (float*)C0;
#pragma unroll
    for (int nf = 0; nf < 4; nf++) {
      int n = bn + wc * 64 + nf * 16 + lanelo;
      float bv = bias[n];
#pragma unroll
      for (int mf = 0; mf < 4; mf++)
#pragma unroll
        for (int q = 0; q < 4; q++) {
          int m = bm + wr * 64 + mf * 16 + lanehi * 4 + q;
          Cf[(size_t)m * H_TOT + n] = acc[mf][nf][q] + bv;
        }
    }
  } else {
    int seg = bn >> 11;
    ushort* dst = (seg == 0) ? (ushort*)C0 : (seg == 1) ? (ushort*)C1 : (ushort*)C2;
    float sc = (seg == 0) ? scale : 1.0f;
#pragma unroll
    for (int nf = 0; nf < 4; nf++) {
      int n = (bn & 2047) + wc * 64 + nf * 16 + lanelo;
      int h = n >> 7, d = n & 127;
#pragma unroll
      for (int mf = 0; mf < 4; mf++)
#pragma unroll
        for (int q = 0; q < 4; q++) {
          int m = bm + wr * 64 + mf * 16 + lanehi * 4 + q;
          int b = m >> 11, s = m & 2047;
          int bh = b * NHEADS + h;
          size_t idx;
          if (seg < 2) {
            idx = (((size_t)(bh * 64 + (s >> 5)) * 8 + (d >> 4)) * 64 +
                   ((d >> 3) & 1) * 32 + (s & 31)) * 8 + (d & 7);
          } else {
            int r = s & 15;
            int e = (r & 3) | ((r >> 1) & 4);
            int hi = (r >> 2) & 1;
            idx = (((size_t)(bh * 64 + (s >> 5)) * 8 + ((s >> 4) & 1) * 4 + (d >> 5)) * 64 +
                   hi * 32 + (d & 31)) * 8 + e;
          }
          dst[idx] = bf16rn(acc[mf][nf][q] * sc);
        }
    }
  }
#undef STAGE
}

// ---------------- flash attention v9: 2 waves x 64 q-rows (2 Q-sets), triple-buffer KV ----------------
// attn was ~75% LDS-BW-bound (80KB/block-body). Each K/V ds_read now feeds TWO MFMAs
// (2 Q-sets) -> LDS reads per q-row halve. Triple buffer lets PV(t-1) read V from
// buf[(t-1)%3] directly (no V register ping-pong; saves 64 VGPR against doubled oacc).
// Buffers in body t: stage->(t+1)%3, QK->t%3, PV->(t+2)%3=(t-1)%3 -- all distinct.
// KV[2]'s V-half zeroed at start (t=0's PV multiplies 0-P by it; avoids 0*Inf=NaN).
__global__ __launch_bounds__(128) void attn_kernel(const ushort* __restrict__ Qf,
                                                   const ushort* __restrict__ Kf,
                                                   const ushort* __restrict__ Vf,
                                                   ushort* __restrict__ Ob) {
  __shared__ __attribute__((aligned(16))) ushort KV[3][8192];  // [buf][K:0..4095 | V:4096..8191]
  __shared__ float lsinv[4][32];                               // [wave*2+set][qcol]
  int lane = threadIdx.x & 63, wave = threadIdx.x >> 6;  // 2 waves
  int hi = lane >> 5;

  // XCD-bijective swizzle (512 % 8 == 0): each XCD gets 64 consecutive swz = 4 heads.
  int bid = blockIdx.x;
  int swz = (bid & 7) * 64 + (bid >> 3);
  int bh = swz >> 4, qt = swz & 15;
  int b = bh >> 4, h = bh & 15;
  int qrow0 = qt * 128 + wave * 64;   // this wave covers qrow0 .. qrow0+63 (2 sets of 32)

  const bf16x8* Qv = reinterpret_cast<const bf16x8*>(Qf) +
                     ((size_t)(bh * 64 + qt * 4 + wave * 2) * 8) * 64 + lane;
  bf16x8 qf0[8], qf1[8];
#pragma unroll
  for (int kc = 0; kc < 8; kc++) { qf0[kc] = Qv[kc * 64]; qf1[kc] = Qv[(8 + kc) * 64]; }

  f32x16 oacc0[4], oacc1[4];
#pragma unroll
  for (int d32 = 0; d32 < 4; d32++)
#pragma unroll
    for (int r = 0; r < 16; r++) { oacc0[d32][r] = 0.f; oacc1[d32][r] = 0.f; }
  float lsum0 = 0.f, lsum1 = 0.f;
  int laneoff = lane * 8;
  const ushort* sbase = wave ? Vf : Kf;  // wave0 stages K chunks, wave1 stages V chunks

#define STAGE(kt, bufsel)                                                                   \
  {                                                                                         \
    size_t gc = ((size_t)(bh * 64 + (kt))) * 8;                                             \
    _Pragma("unroll") for (int i_ = 0; i_ < 8; i_++) {                                      \
      __builtin_amdgcn_global_load_lds(                                                     \
          (const __attribute__((address_space(1))) void*)(sbase + (gc + i_) * 512 + laneoff),\
          (__attribute__((address_space(3))) void*)(&KV[bufsel][(wave * 8 + i_) * 512]),    \
          16, 0, 0);                                                                        \
    }                                                                                       \
  }

  union pu { bf16x8 v; uint32_t u[4]; };
  pu pA00, pA01, pA10, pA11, pB00, pB01, pB10, pB11;  // [A/B side][set][half]
#pragma unroll
  for (int j = 0; j < 4; j++) {
    pA00.u[j] = 0; pA01.u[j] = 0; pA10.u[j] = 0; pA11.u[j] = 0;
  }

  // zero KV[2]'s V-half (read by t=0's PV)
  {
    const bf16x8 bz = {0, 0, 0, 0, 0, 0, 0, 0};
#pragma unroll
    for (int i = 0; i < 4; i++)
      *reinterpret_cast<bf16x8*>(&KV[2][4096 + ((int)threadIdx.x * 4 + i) * 8]) = bz;
  }

  STAGE(0, 0);
  asm volatile("s_waitcnt vmcnt(0)" ::: "memory");
  __syncthreads();

  const int NT = S_LEN / 32;  // 64 (even)

#define BODY(T, PI00, PI01, PI10, PI11, PO00, PO01, PO10, PO11)                             \
  {                                                                                         \
    if ((T) + 1 < NT) STAGE((T) + 1, ((T) + 1) % 3);                                        \
    const ushort* lb = &KV[(T) % 3][0];                                                     \
    const ushort* lbp = &KV[((T) + 2) % 3][0];   /* == (T-1)%3 */                           \
    f32x16 S0, S1;                                                                          \
    _Pragma("unroll") for (int r = 0; r < 16; r++) { S0[r] = 0.f; S1[r] = 0.f; }            \
    __builtin_amdgcn_s_setprio(1);                                                          \
    _Pragma("unroll") for (int kc = 0; kc < 8; kc++) {                                      \
      bf16x8 kfr = *reinterpret_cast<const bf16x8*>(&lb[kc * 512 + laneoff]);               \
      S0 = __builtin_amdgcn_mfma_f32_32x32x16_bf16(kfr, qf0[kc], S0, 0, 0, 0);              \
      S1 = __builtin_amdgcn_mfma_f32_32x32x16_bf16(kfr, qf1[kc], S1, 0, 0, 0);              \
    }                                                                                       \
    _Pragma("unroll") for (int d32 = 0; d32 < 4; d32++) {                                   \
      bf16x8 v0 = *reinterpret_cast<const bf16x8*>(&lbp[4096 + d32 * 512 + laneoff]);       \
      bf16x8 v1 = *reinterpret_cast<const bf16x8*>(&lbp[4096 + (4 + d32) * 512 + laneoff]); \
      oacc0[d32] = __builtin_amdgcn_mfma_f32_32x32x16_bf16(PI00.v, v0, oacc0[d32], 0, 0, 0);\
      oacc0[d32] = __builtin_amdgcn_mfma_f32_32x32x16_bf16(PI01.v, v1, oacc0[d32], 0, 0, 0);\
      oacc1[d32] = __builtin_amdgcn_mfma_f32_32x32x16_bf16(PI10.v, v0, oacc1[d32], 0, 0, 0);\
      oacc1[d32] = __builtin_amdgcn_mfma_f32_32x32x16_bf16(PI11.v, v1, oacc1[d32], 0, 0, 0);\
    }                                                                                       \
    __builtin_amdgcn_s_setprio(0);                                                          \
    _Pragma("unroll") for (int j = 0; j < 4; j++) {                                         \
      float a0 = exp2f(S0[2 * j]), a1 = exp2f(S0[2 * j + 1]);                               \
      float b0 = exp2f(S0[8 + 2 * j]), b1 = exp2f(S0[9 + 2 * j]);                           \
      lsum0 += (a0 + a1) + (b0 + b1);                                                       \
      uint32_t wa, wb;                                                                      \
      asm("v_cvt_pk_bf16_f32 %0, %1, %2" : "=v"(wa) : "v"(a0), "v"(a1));                    \
      asm("v_cvt_pk_bf16_f32 %0, %1, %2" : "=v"(wb) : "v"(b0), "v"(b1));                    \
      PO00.u[j] = wa; PO01.u[j] = wb;                                                       \
      float c0 = exp2f(S1[2 * j]), c1 = exp2f(S1[2 * j + 1]);                               \
      float d0 = exp2f(S1[8 + 2 * j]), d1 = exp2f(S1[9 + 2 * j]);                           \
      lsum1 += (c0 + c1) + (d0 + d1);                                                       \
      uint32_t wc_, wd;                                                                     \
      asm("v_cvt_pk_bf16_f32 %0, %1, %2" : "=v"(wc_) : "v"(c0), "v"(c1));                   \
      asm("v_cvt_pk_bf16_f32 %0, %1, %2" : "=v"(wd) : "v"(d0), "v"(d1));                    \
      PO10.u[j] = wc_; PO11.u[j] = wd;                                                      \
    }                                                                                       \
    asm volatile("s_waitcnt vmcnt(0)" ::: "memory");                                        \
    __syncthreads();                                                                        \
  }

  for (int t = 0; t < NT; t += 2) {
    BODY(t,     pA00, pA01, pA10, pA11, pB00, pB01, pB10, pB11);
    BODY(t + 1, pB00, pB01, pB10, pB11, pA00, pA01, pA10, pA11);
  }
  // final PV: A-side holds P(NT-1); V(NT-1) lives in KV[(NT-1)%3] = KV[0] (untouched since)
  {
    const ushort* lbp = &KV[(NT - 1) % 3][0];
#pragma unroll
    for (int d32 = 0; d32 < 4; d32++) {
      bf16x8 v0 = *reinterpret_cast<const bf16x8*>(&lbp[4096 + d32 * 512 + laneoff]);
      bf16x8 v1 = *reinterpret_cast<const bf16x8*>(&lbp[4096 + (4 + d32) * 512 + laneoff]);
      oacc0[d32] = __builtin_amdgcn_mfma_f32_32x32x16_bf16(pA00.v, v0, oacc0[d32], 0, 0, 0);
      oacc0[d32] = __builtin_amdgcn_mfma_f32_32x32x16_bf16(pA01.v, v1, oacc0[d32], 0, 0, 0);
      oacc1[d32] = __builtin_amdgcn_mfma_f32_32x32x16_bf16(pA10.v, v0, oacc1[d32], 0, 0, 0);
      oacc1[d32] = __builtin_amdgcn_mfma_f32_32x32x16_bf16(pA11.v, v1, oacc1[d32], 0, 0, 0);
    }
  }

  // ---- denominators ----
  float t0 = lsum0 + __shfl_xor(lsum0, 32);
  float t1 = lsum1 + __shfl_xor(lsum1, 32);
  if (lane < 32) {
    lsinv[wave * 2 + 0][lane] = 1.0f / t0;
    lsinv[wave * 2 + 1][lane] = 1.0f / t1;
  }
  __syncthreads();

  // ---- store: D-layout row pattern -> token-major bf16 [b][s][h*128+d] ----
  float ls0[16], ls1[16];
#pragma unroll
  for (int r = 0; r < 16; r++) {
    int row = (r & 3) + 8 * (r >> 2) + 4 * hi;
    ls0[r] = lsinv[wave * 2 + 0][row];
    ls1[r] = lsinv[wave * 2 + 1][row];
  }
#pragma unroll
  for (int d32 = 0; d32 < 4; d32++)
#pragma unroll
    for (int r = 0; r < 16; r++) {
      int row = (r & 3) + 8 * (r >> 2) + 4 * hi;
      size_t idx0 = ((size_t)(b * S_LEN + qrow0 + row)) * H_TOT + h * HDIM + d32 * 32 + (lane & 31);
      size_t idx1 = ((size_t)(b * S_LEN + qrow0 + 32 + row)) * H_TOT + h * HDIM + d32 * 32 + (lane & 31);
      Ob[idx0] = bf16rn(oacc0[d32][r] * ls0[r]);
      Ob[idx1] = bf16rn(oacc1[d32][r] * ls1[r]);
    }
#undef BODY
#undef STAGE
}

// ---------------- host-side launch ----------------
extern "C" void kernel_launch(void* const* d_in, const int* in_sizes, int n_in,
                              void* d_out, int out_size, void* d_ws, size_t ws_size,
                              hipStream_t stream) {
  const float* x  = (const float*)d_in[0];
  const float* Wq = (const float*)d_in[1];
  const float* Wk = (const float*)d_in[2];
  const float* Wv = (const float*)d_in[3];
  const float* Wo = (const float*)d_in[4];
  const float* bo = (const float*)d_in[5];
  float* out = (float*)d_out;

  char* w = (char*)d_ws;
  ushort* xb  = (ushort*)w; w += (size_t)M_TOK * KDIM * 2;
  ushort* Wqb = (ushort*)w; w += (size_t)KDIM * KDIM * 2;   // Wqb,Wkb,Wvb contiguous: fused B
  ushort* Wkb = (ushort*)w; w += (size_t)KDIM * KDIM * 2;
  ushort* Wvb = (ushort*)w; w += (size_t)KDIM * KDIM * 2;
  ushort* Wob = (ushort*)w; w += (size_t)KDIM * KDIM * 2;
  ushort* Qh  = (ushort*)w; w += (size_t)M_TOK * KDIM * 2;
  ushort* Kh  = (ushort*)w; w += (size_t)M_TOK * KDIM * 2;
  ushort* Vt  = (ushort*)w; w += (size_t)M_TOK * KDIM * 2;
  ushort* Ob  = (ushort*)w; w += (size_t)M_TOK * KDIM * 2;

  hipLaunchKernelGGL(cvt_bf16_kernel, dim3(2048), dim3(256), 0, stream, x, xb, M_TOK * KDIM / 4);
  hipLaunchKernelGGL(cvt4_bf16_kernel, dim3(2048), dim3(256), 0, stream,
                     Wq, Wk, Wv, Wo, Wqb, Wkb, Wvb, Wob);

  const float sl = 0.08838834764831845f * 1.4426950408889634f;  // HD^-0.5 * log2(e)

  // fused QKV: M=4096, N=6144 -> 32 x 24 tiles = 768 blocks
  hipLaunchKernelGGL((gemm2<0, 24>), dim3(768), dim3(512), 0, stream,
                     xb, Wqb, (void*)Qh, (void*)Kh, (void*)Vt, (const float*)nullptr, sl);

  hipLaunchKernelGGL(attn_kernel, dim3(512), dim3(128), 0, stream, Qh, Kh, Vt, Ob);

  // output projection: M=4096, N=2048 -> 32 x 8 tiles = 256 blocks
  hipLaunchKernelGGL((gemm2<2, 8>), dim3(256), dim3(512), 0, stream,
                     Ob, Wob, (void*)out, nullptr, nullptr, bo, 1.0f);
}

// Round 15
// 266.940 us; speedup vs baseline: 1.0806x; 1.0806x over previous
//
#include <hip/hip_runtime.h>
#include <hip/hip_bf16.h>
#include <stdint.h>

#define S_LEN 2048
#define NHEADS 16
#define HDIM 128
#define H_TOT 2048
#define BATCH 2
#define M_TOK 4096   // B*S
#define KDIM 2048

typedef __attribute__((ext_vector_type(8))) short bf16x8;
typedef __attribute__((ext_vector_type(4))) float f32x4;
typedef __attribute__((ext_vector_type(16))) float f32x16;

__device__ inline ushort bf16rn(float f) {
  union { float f; uint32_t u; } x; x.f = f;
  uint32_t r = x.u + 0x7FFF + ((x.u >> 16) & 1);
  return (ushort)(r >> 16);
}

// ---------------- fused f32 -> bf16 conversion: x + 4 weights in ONE launch ----------------
__global__ __launch_bounds__(256) void cvt5_bf16_kernel(const float* __restrict__ x,
                                                        const float* __restrict__ w0,
                                                        const float* __restrict__ w1,
                                                        const float* __restrict__ w2,
                                                        const float* __restrict__ w3,
                                                        ushort* __restrict__ xo,
                                                        ushort* __restrict__ o0,
                                                        ushort* __restrict__ o1,
                                                        ushort* __restrict__ o2,
                                                        ushort* __restrict__ o3) {
  const int NX4 = M_TOK * KDIM / 4;   // 1<<21 quads (x)
  const int NW4 = KDIM * KDIM / 4;    // 1<<20 quads (each weight)
  int i = blockIdx.x * blockDim.x + threadIdx.x;
  int stride = gridDim.x * blockDim.x;
  for (; i < NX4 + 4 * NW4; i += stride) {
    const float* in;
    ushort* out;
    int off;
    if (i < NX4) {
      in = x; out = xo; off = i;
    } else {
      int j = i - NX4;
      int seg = j >> 20;
      off = j & (NW4 - 1);
      in = (seg == 0) ? w0 : (seg == 1) ? w1 : (seg == 2) ? w2 : w3;
      out = (seg == 0) ? o0 : (seg == 1) ? o1 : (seg == 2) ? o2 : o3;
    }
    float4 v = reinterpret_cast<const float4*>(in)[off];
    ushort4 o;
    o.x = bf16rn(v.x); o.y = bf16rn(v.y); o.z = bf16rn(v.z); o.w = bf16rn(v.w);
    reinterpret_cast<ushort4*>(out)[off] = o;
  }
}

// ---------------- pipelined NT GEMM (round-6/13 best: 127.5us QKV) ----------------
// BM=128 BN=256 BK=64, 512 thr, triple-buffer, counted vmcnt(6), raw s_barrier.
// MODE 0: fused QKV epilogue -> fragment-native Q/K/V layouts (seg = bn>>11)
// MODE 2: f32 [m][n] + bias[n]
template<int MODE, int NBX>
__global__ __launch_bounds__(512) void gemm2(const ushort* __restrict__ A,
                                             const ushort* __restrict__ Bw,
                                             void* __restrict__ C0,
                                             void* __restrict__ C1,
                                             void* __restrict__ C2,
                                             const float* __restrict__ bias,
                                             float scale) {
  __shared__ __attribute__((aligned(16))) char lds[3 * 49152];  // [buf][A:16KB | B:32KB]
  const int K = KDIM;
  const int NKT = K / 64;  // 32
  int tid = threadIdx.x;
  int wave = tid >> 6, lane = tid & 63;
  int lanelo = lane & 15, lanehi = lane >> 4;
  int wr = wave >> 2, wc = wave & 3;  // 2M x 4N waves, 64x64 output each

  int bid = blockIdx.x;
  const int CHX = NBX / 8;
  int ii = bid >> 3;
  int bx = (bid & 7) * CHX + (ii % CHX);
  int by = ii / CHX;
  int bm = by * 128, bn = bx * 256;

  const ushort* srcA[2];
  const ushort* srcB[4];
#pragma unroll
  for (int i = 0; i < 2; i++) {
    int c = i * 512 + tid, row = c >> 3, slot = c & 7;
    srcA[i] = A + (size_t)(bm + row) * K + ((slot ^ (row & 7)) * 8);
  }
#pragma unroll
  for (int i = 0; i < 4; i++) {
    int c = i * 512 + tid, row = c >> 3, slot = c & 7;
    srcB[i] = Bw + (size_t)(bn + row) * K + ((slot ^ (row & 7)) * 8);
  }

#define STAGE(tile, buf)                                                                    \
  {                                                                                         \
    char* dA = lds + (buf) * 49152 + (size_t)tid * 16;                                      \
    char* dB = lds + (buf) * 49152 + 16384 + (size_t)tid * 16;                              \
    _Pragma("unroll") for (int i_ = 0; i_ < 2; i_++)                                        \
      __builtin_amdgcn_global_load_lds(                                                     \
          (const __attribute__((address_space(1))) void*)(srcA[i_] + (tile) * 64),          \
          (__attribute__((address_space(3))) void*)(dA + i_ * 8192), 16, 0, 0);             \
    _Pragma("unroll") for (int i_ = 0; i_ < 4; i_++)                                        \
      __builtin_amdgcn_global_load_lds(                                                     \
          (const __attribute__((address_space(1))) void*)(srcB[i_] + (tile) * 64),          \
          (__attribute__((address_space(3))) void*)(dB + i_ * 8192), 16, 0, 0);             \
  }

  f32x4 acc[4][4];
#pragma unroll
  for (int i = 0; i < 4; i++)
#pragma unroll
    for (int j = 0; j < 4; j++) acc[i][j] = (f32x4){0.f, 0.f, 0.f, 0.f};

  STAGE(0, 0);
  STAGE(1, 1);
  asm volatile("s_waitcnt vmcnt(6)" ::: "memory");
  __builtin_amdgcn_s_barrier();
  __builtin_amdgcn_sched_barrier(0);

  for (int t = 0; t < NKT; t++) {
    STAGE((t + 2) & (NKT - 1), (t + 2) % 3);

    const ushort* bufc = (const ushort*)(lds + (t % 3) * 49152);

    bf16x8 bfr[4][2];
#pragma unroll
    for (int nf = 0; nf < 4; nf++)
#pragma unroll
      for (int kh = 0; kh < 2; kh++) {
        int row = wc * 64 + nf * 16 + lanelo;
        int slot = (kh * 4 + lanehi) ^ (row & 7);
        bfr[nf][kh] = *reinterpret_cast<const bf16x8*>(&bufc[8192 + row * 64 + slot * 8]);
      }

    __builtin_amdgcn_s_setprio(1);
#pragma unroll
    for (int mf = 0; mf < 4; mf++) {
      int row = wr * 64 + mf * 16 + lanelo;
      bf16x8 af[2];
#pragma unroll
      for (int kh = 0; kh < 2; kh++) {
        int slot = (kh * 4 + lanehi) ^ (row & 7);
        af[kh] = *reinterpret_cast<const bf16x8*>(&bufc[row * 64 + slot * 8]);
      }
#pragma unroll
      for (int nf = 0; nf < 4; nf++)
#pragma unroll
        for (int kh = 0; kh < 2; kh++)
          acc[mf][nf] = __builtin_amdgcn_mfma_f32_16x16x32_bf16(af[kh], bfr[nf][kh],
                                                                acc[mf][nf], 0, 0, 0);
    }
    __builtin_amdgcn_s_setprio(0);

    asm volatile("s_waitcnt vmcnt(6)" ::: "memory");
    __builtin_amdgcn_s_barrier();
    __builtin_amdgcn_sched_barrier(0);
  }

  // ---------------- epilogue ----------------
  if (MODE == 2) {
    float* Cf = (float*)C0;
#pragma unroll
    for (int nf = 0; nf < 4; nf++) {
      int n = bn + wc * 64 + nf * 16 + lanelo;
      float bv = bias[n];
#pragma unroll
      for (int mf = 0; mf < 4; mf++)
#pragma unroll
        for (int q = 0; q < 4; q++) {
          int m = bm + wr * 64 + mf * 16 + lanehi * 4 + q;
          Cf[(size_t)m * H_TOT + n] = acc[mf][nf][q] + bv;
        }
    }
  } else {
    int seg = bn >> 11;
    ushort* dst = (seg == 0) ? (ushort*)C0 : (seg == 1) ? (ushort*)C1 : (ushort*)C2;
    float sc = (seg == 0) ? scale : 1.0f;
#pragma unroll
    for (int nf = 0; nf < 4; nf++) {
      int n = (bn & 2047) + wc * 64 + nf * 16 + lanelo;
      int h = n >> 7, d = n & 127;
#pragma unroll
      for (int mf = 0; mf < 4; mf++)
#pragma unroll
        for (int q = 0; q < 4; q++) {
          int m = bm + wr * 64 + mf * 16 + lanehi * 4 + q;
          int b = m >> 11, s = m & 2047;
          int bh = b * NHEADS + h;
          size_t idx;
          if (seg < 2) {
            idx = (((size_t)(bh * 64 + (s >> 5)) * 8 + (d >> 4)) * 64 +
                   ((d >> 3) & 1) * 32 + (s & 31)) * 8 + (d & 7);
          } else {
            int r = s & 15;
            int e = (r & 3) | ((r >> 1) & 4);
            int hi = (r >> 2) & 1;
            idx = (((size_t)(bh * 64 + (s >> 5)) * 8 + ((s >> 4) & 1) * 4 + (d >> 5)) * 64 +
                   hi * 32 + (d & 31)) * 8 + e;
          }
          dst[idx] = bf16rn(acc[mf][nf][q] * sc);
        }
    }
  }
#undef STAGE
}

// ---------------- flash attention v8 (round-13 best): 4-wave geometry + deferred-PV ----------------
// 4 waves/block, 32 q-rows/wave, 512 blocks, double-buffered KV (32KB -> 4 blocks/CU,
// 16 waves/CU). Staging split over 4 waves (4 issues/wave). Deferred PV: iteration t
// issues QK(t) and PV(t-1) back-to-back; P/V of previous tile in ping-pong registers.
__global__ __launch_bounds__(256) void attn_kernel(const ushort* __restrict__ Qf,
                                                   const ushort* __restrict__ Kf,
                                                   const ushort* __restrict__ Vf,
                                                   ushort* __restrict__ Ob) {
  __shared__ __attribute__((aligned(16))) ushort KV[2][8192];  // [buf][K:0..4095 | V:4096..8191]
  __shared__ float lsinv[4][32];
  int lane = threadIdx.x & 63, wave = threadIdx.x >> 6;  // 4 waves
  int hi = lane >> 5;

  // XCD-bijective swizzle (512 % 8 == 0): each XCD gets 64 consecutive swz = 4 heads.
  int bid = blockIdx.x;
  int swz = (bid & 7) * 64 + (bid >> 3);
  int bh = swz >> 4, qt = swz & 15;
  int b = bh >> 4, h = bh & 15;
  int qrow0 = qt * 128 + wave * 32;

  const bf16x8* Qv = reinterpret_cast<const bf16x8*>(Qf) +
                     ((size_t)(bh * 64 + qt * 4 + wave) * 8) * 64 + lane;
  bf16x8 qf[8];
#pragma unroll
  for (int kc = 0; kc < 8; kc++) qf[kc] = Qv[kc * 64];

  f32x16 oacc[4];
#pragma unroll
  for (int d32 = 0; d32 < 4; d32++)
#pragma unroll
    for (int r = 0; r < 16; r++) oacc[d32][r] = 0.f;
  float lsum = 0.f;
  int laneoff = lane * 8;
  const ushort* Kbase = Kf;
  const ushort* Vbase = Vf;

  // wave w stages chunks 4w..4w+3 (c<8 -> K chunk c, c>=8 -> V chunk c-8): 4 issues/wave
#define STAGE(kt, bufsel)                                                                  \
  {                                                                                        \
    size_t gchunk = ((size_t)(bh * 64 + (kt))) * 8;                                        \
    _Pragma("unroll")                                                                      \
    for (int i_ = 0; i_ < 4; i_++) {                                                       \
      int cc = wave * 4 + i_;                                                              \
      const ushort* src = (cc < 8) ? (Kbase + (gchunk + cc) * 512 + laneoff)               \
                                   : (Vbase + (gchunk + (cc - 8)) * 512 + laneoff);        \
      __builtin_amdgcn_global_load_lds((const __attribute__((address_space(1))) void*)src, \
                                       (__attribute__((address_space(3))) void*)           \
                                           (&KV[bufsel][cc * 512]),                        \
                                       16, 0, 0);                                          \
    }                                                                                      \
  }

  union pu { bf16x8 v; uint32_t u[4]; };
  pu paA0, paA1, paB0, paB1;
  bf16x8 vrA[8], vrB[8];
  const bf16x8 bz = {0, 0, 0, 0, 0, 0, 0, 0};
#pragma unroll
  for (int j = 0; j < 4; j++) { paA0.u[j] = 0; paA1.u[j] = 0; }
#pragma unroll
  for (int i = 0; i < 8; i++) vrA[i] = bz;   // first PV is a 0*0 no-op

  STAGE(0, 0);
  asm volatile("s_waitcnt vmcnt(0)" ::: "memory");
  __syncthreads();

  const int NT = S_LEN / 32;  // 64 (even)

#define BODY(T, PI0, PI1, VI, PO0, PO1, VO)                                                 \
  {                                                                                         \
    if ((T) + 1 < NT) STAGE((T) + 1, ((T) + 1) & 1);                                        \
    const ushort* lb = &KV[(T) & 1][0];                                                     \
    f32x16 S;                                                                               \
    _Pragma("unroll") for (int r = 0; r < 16; r++) S[r] = 0.f;                              \
    __builtin_amdgcn_s_setprio(1);                                                          \
    _Pragma("unroll") for (int kc = 0; kc < 8; kc++) {                                      \
      bf16x8 kfr = *reinterpret_cast<const bf16x8*>(&lb[kc * 512 + laneoff]);               \
      S = __builtin_amdgcn_mfma_f32_32x32x16_bf16(kfr, qf[kc], S, 0, 0, 0);                 \
    }                                                                                       \
    _Pragma("unroll") for (int d32 = 0; d32 < 4; d32++) {                                   \
      oacc[d32] = __builtin_amdgcn_mfma_f32_32x32x16_bf16(PI0.v, VI[d32], oacc[d32], 0, 0, 0); \
      oacc[d32] = __builtin_amdgcn_mfma_f32_32x32x16_bf16(PI1.v, VI[4 + d32], oacc[d32], 0, 0, 0); \
    }                                                                                       \
    __builtin_amdgcn_s_setprio(0);                                                          \
    float p_[16];                                                                           \
    _Pragma("unroll") for (int r = 0; r < 16; r++) { p_[r] = exp2f(S[r]); lsum += p_[r]; }  \
    _Pragma("unroll") for (int j = 0; j < 4; j++) {                                         \
      uint32_t w0_, w1_;                                                                    \
      asm("v_cvt_pk_bf16_f32 %0, %1, %2" : "=v"(w0_) : "v"(p_[2 * j]), "v"(p_[2 * j + 1])); \
      asm("v_cvt_pk_bf16_f32 %0, %1, %2" : "=v"(w1_) : "v"(p_[8 + 2 * j]), "v"(p_[9 + 2 * j])); \
      PO0.u[j] = w0_; PO1.u[j] = w1_;                                                       \
    }                                                                                       \
    _Pragma("unroll") for (int i_ = 0; i_ < 8; i_++)                                        \
      VO[i_] = *reinterpret_cast<const bf16x8*>(&lb[4096 + i_ * 512 + laneoff]);            \
    asm volatile("s_waitcnt vmcnt(0)" ::: "memory");                                        \
    __syncthreads();                                                                        \
  }

  for (int t = 0; t < NT; t += 2) {
    BODY(t,     paA0, paA1, vrA, paB0, paB1, vrB);
    BODY(t + 1, paB0, paB1, vrB, paA0, paA1, vrA);
  }
  // final PV: A-side holds P(NT-1), V(NT-1)
#pragma unroll
  for (int d32 = 0; d32 < 4; d32++) {
    oacc[d32] = __builtin_amdgcn_mfma_f32_32x32x16_bf16(paA0.v, vrA[d32], oacc[d32], 0, 0, 0);
    oacc[d32] = __builtin_amdgcn_mfma_f32_32x32x16_bf16(paA1.v, vrA[4 + d32], oacc[d32], 0, 0, 0);
  }

  // ---- denominator: q-row lane&31 total = own + partner(lane^32) ----
  float total = lsum + __shfl_xor(lsum, 32);
  if (lane < 32) lsinv[wave][lane] = 1.0f / total;
  __syncthreads();

  // ---- store: D-layout row pattern -> token-major bf16 [b][s][h*128+d] ----
  float ls[16];
#pragma unroll
  for (int r = 0; r < 16; r++) ls[r] = lsinv[wave][(r & 3) + 8 * (r >> 2) + 4 * hi];
#pragma unroll
  for (int d32 = 0; d32 < 4; d32++)
#pragma unroll
    for (int r = 0; r < 16; r++) {
      int row = (r & 3) + 8 * (r >> 2) + 4 * hi;
      size_t idx = ((size_t)(b * S_LEN + qrow0 + row)) * H_TOT + h * HDIM + d32 * 32 + (lane & 31);
      Ob[idx] = bf16rn(oacc[d32][r] * ls[r]);
    }
#undef BODY
#undef STAGE
}

// ---------------- host-side launch ----------------
extern "C" void kernel_launch(void* const* d_in, const int* in_sizes, int n_in,
                              void* d_out, int out_size, void* d_ws, size_t ws_size,
                              hipStream_t stream) {
  const float* x  = (const float*)d_in[0];
  const float* Wq = (const float*)d_in[1];
  const float* Wk = (const float*)d_in[2];
  const float* Wv = (const float*)d_in[3];
  const float* Wo = (const float*)d_in[4];
  const float* bo = (const float*)d_in[5];
  float* out = (float*)d_out;

  char* w = (char*)d_ws;
  ushort* xb  = (ushort*)w; w += (size_t)M_TOK * KDIM * 2;
  ushort* Wqb = (ushort*)w; w += (size_t)KDIM * KDIM * 2;   // Wqb,Wkb,Wvb contiguous: fused B
  ushort* Wkb = (ushort*)w; w += (size_t)KDIM * KDIM * 2;
  ushort* Wvb = (ushort*)w; w += (size_t)KDIM * KDIM * 2;
  ushort* Wob = (ushort*)w; w += (size_t)KDIM * KDIM * 2;
  ushort* Qh  = (ushort*)w; w += (size_t)M_TOK * KDIM * 2;
  ushort* Kh  = (ushort*)w; w += (size_t)M_TOK * KDIM * 2;
  ushort* Vt  = (ushort*)w; w += (size_t)M_TOK * KDIM * 2;
  ushort* Ob  = (ushort*)w; w += (size_t)M_TOK * KDIM * 2;

  // one fused conversion launch: x + Wq + Wk + Wv + Wo
  hipLaunchKernelGGL(cvt5_bf16_kernel, dim3(2048), dim3(256), 0, stream,
                     x, Wq, Wk, Wv, Wo, xb, Wqb, Wkb, Wvb, Wob);

  const float sl = 0.08838834764831845f * 1.4426950408889634f;  // HD^-0.5 * log2(e)

  // fused QKV: M=4096, N=6144 -> 32 x 24 tiles = 768 blocks
  hipLaunchKernelGGL((gemm2<0, 24>), dim3(768), dim3(512), 0, stream,
                     xb, Wqb, (void*)Qh, (void*)Kh, (void*)Vt, (const float*)nullptr, sl);

  hipLaunchKernelGGL(attn_kernel, dim3(512), dim3(256), 0, stream, Qh, Kh, Vt, Ob);

  // output projection: M=4096, N=2048 -> 32 x 8 tiles = 256 blocks
  hipLaunchKernelGGL((gemm2<2, 8>), dim3(256), dim3(512), 0, stream,
                     Ob, Wob, (void*)out, nullptr, nullptr, bo, 1.0f);
}

// Round 16
// 265.826 us; speedup vs baseline: 1.0852x; 1.0042x over previous
//
#include <hip/hip_runtime.h>
#include <hip/hip_bf16.h>
#include <stdint.h>

#define S_LEN 2048
#define NHEADS 16
#define HDIM 128
#define H_TOT 2048
#define BATCH 2
#define M_TOK 4096   // B*S
#define KDIM 2048

typedef __attribute__((ext_vector_type(8))) short bf16x8;
typedef __attribute__((ext_vector_type(4))) float f32x4;
typedef __attribute__((ext_vector_type(16))) float f32x16;

__device__ inline ushort bf16rn(float f) {
  union { float f; uint32_t u; } x; x.f = f;
  uint32_t r = x.u + 0x7FFF + ((x.u >> 16) & 1);
  return (ushort)(r >> 16);
}

// ---------------- fused f32 -> bf16 conversion: x + 4 weights in ONE launch ----------------
__global__ __launch_bounds__(256) void cvt5_bf16_kernel(const float* __restrict__ x,
                                                        const float* __restrict__ w0,
                                                        const float* __restrict__ w1,
                                                        const float* __restrict__ w2,
                                                        const float* __restrict__ w3,
                                                        ushort* __restrict__ xo,
                                                        ushort* __restrict__ o0,
                                                        ushort* __restrict__ o1,
                                                        ushort* __restrict__ o2,
                                                        ushort* __restrict__ o3) {
  const int NX4 = M_TOK * KDIM / 4;   // 1<<21 quads (x)
  const int NW4 = KDIM * KDIM / 4;    // 1<<20 quads (each weight)
  int i = blockIdx.x * blockDim.x + threadIdx.x;
  int stride = gridDim.x * blockDim.x;
  for (; i < NX4 + 4 * NW4; i += stride) {
    const float* in;
    ushort* out;
    int off;
    if (i < NX4) {
      in = x; out = xo; off = i;
    } else {
      int j = i - NX4;
      int seg = j >> 20;
      off = j & (NW4 - 1);
      in = (seg == 0) ? w0 : (seg == 1) ? w1 : (seg == 2) ? w2 : w3;
      out = (seg == 0) ? o0 : (seg == 1) ? o1 : (seg == 2) ? o2 : o3;
    }
    float4 v = reinterpret_cast<const float4*>(in)[off];
    ushort4 o;
    o.x = bf16rn(v.x); o.y = bf16rn(v.y); o.z = bf16rn(v.z); o.w = bf16rn(v.w);
    reinterpret_cast<ushort4*>(out)[off] = o;
  }
}

// ---------------- pipelined NT GEMM (round-6/13 best: 127.5us QKV) ----------------
// BM=128 BN=256 BK=64, 512 thr, triple-buffer, counted vmcnt(6), raw s_barrier.
// MODE 0: fused QKV epilogue -> fragment-native Q/K/V layouts (seg = bn>>11)
// MODE 2: f32 [m][n] + bias[n]
template<int MODE, int NBX>
__global__ __launch_bounds__(512) void gemm2(const ushort* __restrict__ A,
                                             const ushort* __restrict__ Bw,
                                             void* __restrict__ C0,
                                             void* __restrict__ C1,
                                             void* __restrict__ C2,
                                             const float* __restrict__ bias,
                                             float scale) {
  __shared__ __attribute__((aligned(16))) char lds[3 * 49152];  // [buf][A:16KB | B:32KB]
  const int K = KDIM;
  const int NKT = K / 64;  // 32
  int tid = threadIdx.x;
  int wave = tid >> 6, lane = tid & 63;
  int lanelo = lane & 15, lanehi = lane >> 4;
  int wr = wave >> 2, wc = wave & 3;  // 2M x 4N waves, 64x64 output each

  int bid = blockIdx.x;
  const int CHX = NBX / 8;
  int ii = bid >> 3;
  int bx = (bid & 7) * CHX + (ii % CHX);
  int by = ii / CHX;
  int bm = by * 128, bn = bx * 256;

  const ushort* srcA[2];
  const ushort* srcB[4];
#pragma unroll
  for (int i = 0; i < 2; i++) {
    int c = i * 512 + tid, row = c >> 3, slot = c & 7;
    srcA[i] = A + (size_t)(bm + row) * K + ((slot ^ (row & 7)) * 8);
  }
#pragma unroll
  for (int i = 0; i < 4; i++) {
    int c = i * 512 + tid, row = c >> 3, slot = c & 7;
    srcB[i] = Bw + (size_t)(bn + row) * K + ((slot ^ (row & 7)) * 8);
  }

#define STAGE(tile, buf)                                                                    \
  {                                                                                         \
    char* dA = lds + (buf) * 49152 + (size_t)tid * 16;                                      \
    char* dB = lds + (buf) * 49152 + 16384 + (size_t)tid * 16;                              \
    _Pragma("unroll") for (int i_ = 0; i_ < 2; i_++)                                        \
      __builtin_amdgcn_global_load_lds(                                                     \
          (const __attribute__((address_space(1))) void*)(srcA[i_] + (tile) * 64),          \
          (__attribute__((address_space(3))) void*)(dA + i_ * 8192), 16, 0, 0);             \
    _Pragma("unroll") for (int i_ = 0; i_ < 4; i_++)                                        \
      __builtin_amdgcn_global_load_lds(                                                     \
          (const __attribute__((address_space(1))) void*)(srcB[i_] + (tile) * 64),          \
          (__attribute__((address_space(3))) void*)(dB + i_ * 8192), 16, 0, 0);             \
  }

  f32x4 acc[4][4];
#pragma unroll
  for (int i = 0; i < 4; i++)
#pragma unroll
    for (int j = 0; j < 4; j++) acc[i][j] = (f32x4){0.f, 0.f, 0.f, 0.f};

  STAGE(0, 0);
  STAGE(1, 1);
  asm volatile("s_waitcnt vmcnt(6)" ::: "memory");
  __builtin_amdgcn_s_barrier();
  __builtin_amdgcn_sched_barrier(0);

  for (int t = 0; t < NKT; t++) {
    STAGE((t + 2) & (NKT - 1), (t + 2) % 3);

    const ushort* bufc = (const ushort*)(lds + (t % 3) * 49152);

    bf16x8 bfr[4][2];
#pragma unroll
    for (int nf = 0; nf < 4; nf++)
#pragma unroll
      for (int kh = 0; kh < 2; kh++) {
        int row = wc * 64 + nf * 16 + lanelo;
        int slot = (kh * 4 + lanehi) ^ (row & 7);
        bfr[nf][kh] = *reinterpret_cast<const bf16x8*>(&bufc[8192 + row * 64 + slot * 8]);
      }

    __builtin_amdgcn_s_setprio(1);
#pragma unroll
    for (int mf = 0; mf < 4; mf++) {
      int row = wr * 64 + mf * 16 + lanelo;
      bf16x8 af[2];
#pragma unroll
      for (int kh = 0; kh < 2; kh++) {
        int slot = (kh * 4 + lanehi) ^ (row & 7);
        af[kh] = *reinterpret_cast<const bf16x8*>(&bufc[row * 64 + slot * 8]);
      }
#pragma unroll
      for (int nf = 0; nf < 4; nf++)
#pragma unroll
        for (int kh = 0; kh < 2; kh++)
          acc[mf][nf] = __builtin_amdgcn_mfma_f32_16x16x32_bf16(af[kh], bfr[nf][kh],
                                                                acc[mf][nf], 0, 0, 0);
    }
    __builtin_amdgcn_s_setprio(0);

    asm volatile("s_waitcnt vmcnt(6)" ::: "memory");
    __builtin_amdgcn_s_barrier();
    __builtin_amdgcn_sched_barrier(0);
  }

  // ---------------- epilogue ----------------
  if (MODE == 2) {
    float* Cf = (float*)C0;
#pragma unroll
    for (int nf = 0; nf < 4; nf++) {
      int n = bn + wc * 64 + nf * 16 + lanelo;
      float bv = bias[n];
#pragma unroll
      for (int mf = 0; mf < 4; mf++)
#pragma unroll
        for (int q = 0; q < 4; q++) {
          int m = bm + wr * 64 + mf * 16 + lanehi * 4 + q;
          Cf[(size_t)m * H_TOT + n] = acc[mf][nf][q] + bv;
        }
    }
  } else {
    int seg = bn >> 11;
    ushort* dst = (seg == 0) ? (ushort*)C0 : (seg == 1) ? (ushort*)C1 : (ushort*)C2;
    float sc = (seg == 0) ? scale : 1.0f;
#pragma unroll
    for (int nf = 0; nf < 4; nf++) {
      int n = (bn & 2047) + wc * 64 + nf * 16 + lanelo;
      int h = n >> 7, d = n & 127;
#pragma unroll
      for (int mf = 0; mf < 4; mf++)
#pragma unroll
        for (int q = 0; q < 4; q++) {
          int m = bm + wr * 64 + mf * 16 + lanehi * 4 + q;
          int b = m >> 11, s = m & 2047;
          int bh = b * NHEADS + h;
          size_t idx;
          if (seg < 2) {
            idx = (((size_t)(bh * 64 + (s >> 5)) * 8 + (d >> 4)) * 64 +
                   ((d >> 3) & 1) * 32 + (s & 31)) * 8 + (d & 7);
          } else {
            int r = s & 15;
            int e = (r & 3) | ((r >> 1) & 4);
            int hi = (r >> 2) & 1;
            idx = (((size_t)(bh * 64 + (s >> 5)) * 8 + ((s >> 4) & 1) * 4 + (d >> 5)) * 64 +
                   hi * 32 + (d & 31)) * 8 + e;
          }
          dst[idx] = bf16rn(acc[mf][nf][q] * sc);
        }
    }
  }
#undef STAGE
}

// ---------------- flash attention v10: v8 + V direct-from-global (fragment-native) ----------------
// K staged in LDS (shared by 4 waves, 2 issues/wave); V read straight from its
// fragment-native global layout (identical address pattern to the old ds_read: one
// fully-coalesced 1KB buffer-load per chunk). Deferred-PV ping-pong gives V(t) a full
// body (~1100cy) to land before PV(t) in body t+1. DMA writes halve (8KB/body),
// ds_reads halve (8/wave), LDS drops to 16.5KB.
__global__ __launch_bounds__(256) void attn_kernel(const ushort* __restrict__ Qf,
                                                   const ushort* __restrict__ Kf,
                                                   const ushort* __restrict__ Vf,
                                                   ushort* __restrict__ Ob) {
  __shared__ __attribute__((aligned(16))) ushort Kl[2][4096];  // K tile double buffer
  __shared__ float lsinv[4][32];
  int lane = threadIdx.x & 63, wave = threadIdx.x >> 6;  // 4 waves
  int hi = lane >> 5;

  // XCD-bijective swizzle (512 % 8 == 0): each XCD gets 64 consecutive swz = 4 heads.
  int bid = blockIdx.x;
  int swz = (bid & 7) * 64 + (bid >> 3);
  int bh = swz >> 4, qt = swz & 15;
  int b = bh >> 4, h = bh & 15;
  int qrow0 = qt * 128 + wave * 32;

  const bf16x8* Qv = reinterpret_cast<const bf16x8*>(Qf) +
                     ((size_t)(bh * 64 + qt * 4 + wave) * 8) * 64 + lane;
  bf16x8 qf[8];
#pragma unroll
  for (int kc = 0; kc < 8; kc++) qf[kc] = Qv[kc * 64];

  f32x16 oacc[4];
#pragma unroll
  for (int d32 = 0; d32 < 4; d32++)
#pragma unroll
    for (int r = 0; r < 16; r++) oacc[d32][r] = 0.f;
  float lsum = 0.f;
  int laneoff = lane * 8;
  // V fragment-native base for this head, lane folded in: chunk (kt*8 + i) at [chunk*64]
  const bf16x8* Vv = reinterpret_cast<const bf16x8*>(Vf) + ((size_t)bh * 64 * 8) * 64 + lane;

  // wave w stages K chunks 2w, 2w+1 (2 issues/wave)
#define STAGE(kt, bufsel)                                                                  \
  {                                                                                        \
    size_t gchunk = ((size_t)(bh * 64 + (kt))) * 8;                                        \
    _Pragma("unroll")                                                                      \
    for (int i_ = 0; i_ < 2; i_++) {                                                       \
      int cc = wave * 2 + i_;                                                              \
      __builtin_amdgcn_global_load_lds(                                                    \
          (const __attribute__((address_space(1))) void*)(Kf + (gchunk + cc) * 512 +       \
                                                          laneoff),                        \
          (__attribute__((address_space(3))) void*)(&Kl[bufsel][cc * 512]), 16, 0, 0);     \
    }                                                                                      \
  }

  union pu { bf16x8 v; uint32_t u[4]; };
  pu paA0, paA1, paB0, paB1;
  bf16x8 vrA[8], vrB[8];
  const bf16x8 bz = {0, 0, 0, 0, 0, 0, 0, 0};
#pragma unroll
  for (int j = 0; j < 4; j++) { paA0.u[j] = 0; paA1.u[j] = 0; }
#pragma unroll
  for (int i = 0; i < 8; i++) vrA[i] = bz;   // first PV is a 0*0 no-op

  STAGE(0, 0);
  asm volatile("s_waitcnt vmcnt(0)" ::: "memory");
  __syncthreads();

  const int NT = S_LEN / 32;  // 64 (even)

#define BODY(T, PI0, PI1, VI, PO0, PO1, VO)                                                 \
  {                                                                                         \
    if ((T) + 1 < NT) STAGE((T) + 1, ((T) + 1) & 1);                                        \
    _Pragma("unroll") for (int i_ = 0; i_ < 8; i_++)                                        \
      VO[i_] = Vv[((size_t)(T) * 8 + i_) * 64];   /* V(T): coalesced, lands by body end */  \
    const ushort* lb = &Kl[(T) & 1][0];                                                     \
    f32x16 S;                                                                               \
    _Pragma("unroll") for (int r = 0; r < 16; r++) S[r] = 0.f;                              \
    __builtin_amdgcn_s_setprio(1);                                                          \
    _Pragma("unroll") for (int kc = 0; kc < 8; kc++) {                                      \
      bf16x8 kfr = *reinterpret_cast<const bf16x8*>(&lb[kc * 512 + laneoff]);               \
      S = __builtin_amdgcn_mfma_f32_32x32x16_bf16(kfr, qf[kc], S, 0, 0, 0);                 \
    }                                                                                       \
    _Pragma("unroll") for (int d32 = 0; d32 < 4; d32++) {                                   \
      oacc[d32] = __builtin_amdgcn_mfma_f32_32x32x16_bf16(PI0.v, VI[d32], oacc[d32], 0, 0, 0); \
      oacc[d32] = __builtin_amdgcn_mfma_f32_32x32x16_bf16(PI1.v, VI[4 + d32], oacc[d32], 0, 0, 0); \
    }                                                                                       \
    __builtin_amdgcn_s_setprio(0);                                                          \
    float p_[16];                                                                           \
    _Pragma("unroll") for (int r = 0; r < 16; r++) { p_[r] = exp2f(S[r]); lsum += p_[r]; }  \
    _Pragma("unroll") for (int j = 0; j < 4; j++) {                                         \
      uint32_t w0_, w1_;                                                                    \
      asm("v_cvt_pk_bf16_f32 %0, %1, %2" : "=v"(w0_) : "v"(p_[2 * j]), "v"(p_[2 * j + 1])); \
      asm("v_cvt_pk_bf16_f32 %0, %1, %2" : "=v"(w1_) : "v"(p_[8 + 2 * j]), "v"(p_[9 + 2 * j])); \
      PO0.u[j] = w0_; PO1.u[j] = w1_;                                                       \
    }                                                                                       \
    asm volatile("s_waitcnt vmcnt(0)" ::: "memory");                                        \
    __syncthreads();                                                                        \
  }

  for (int t = 0; t < NT; t += 2) {
    BODY(t,     paA0, paA1, vrA, paB0, paB1, vrB);
    BODY(t + 1, paB0, paB1, vrB, paA0, paA1, vrA);
  }
  // final PV: A-side holds P(NT-1), V(NT-1)
#pragma unroll
  for (int d32 = 0; d32 < 4; d32++) {
    oacc[d32] = __builtin_amdgcn_mfma_f32_32x32x16_bf16(paA0.v, vrA[d32], oacc[d32], 0, 0, 0);
    oacc[d32] = __builtin_amdgcn_mfma_f32_32x32x16_bf16(paA1.v, vrA[4 + d32], oacc[d32], 0, 0, 0);
  }

  // ---- denominator: q-row lane&31 total = own + partner(lane^32) ----
  float total = lsum + __shfl_xor(lsum, 32);
  if (lane < 32) lsinv[wave][lane] = 1.0f / total;
  __syncthreads();

  // ---- store: D-layout row pattern -> token-major bf16 [b][s][h*128+d] ----
  float ls[16];
#pragma unroll
  for (int r = 0; r < 16; r++) ls[r] = lsinv[wave][(r & 3) + 8 * (r >> 2) + 4 * hi];
#pragma unroll
  for (int d32 = 0; d32 < 4; d32++)
#pragma unroll
    for (int r = 0; r < 16; r++) {
      int row = (r & 3) + 8 * (r >> 2) + 4 * hi;
      size_t idx = ((size_t)(b * S_LEN + qrow0 + row)) * H_TOT + h * HDIM + d32 * 32 + (lane & 31);
      Ob[idx] = bf16rn(oacc[d32][r] * ls[r]);
    }
#undef BODY
#undef STAGE
}

// ---------------- host-side launch ----------------
extern "C" void kernel_launch(void* const* d_in, const int* in_sizes, int n_in,
                              void* d_out, int out_size, void* d_ws, size_t ws_size,
                              hipStream_t stream) {
  const float* x  = (const float*)d_in[0];
  const float* Wq = (const float*)d_in[1];
  const float* Wk = (const float*)d_in[2];
  const float* Wv = (const float*)d_in[3];
  const float* Wo = (const float*)d_in[4];
  const float* bo = (const float*)d_in[5];
  float* out = (float*)d_out;

  char* w = (char*)d_ws;
  ushort* xb  = (ushort*)w; w += (size_t)M_TOK * KDIM * 2;
  ushort* Wqb = (ushort*)w; w += (size_t)KDIM * KDIM * 2;   // Wqb,Wkb,Wvb contiguous: fused B
  ushort* Wkb = (ushort*)w; w += (size_t)KDIM * KDIM * 2;
  ushort* Wvb = (ushort*)w; w += (size_t)KDIM * KDIM * 2;
  ushort* Wob = (ushort*)w; w += (size_t)KDIM * KDIM * 2;
  ushort* Qh  = (ushort*)w; w += (size_t)M_TOK * KDIM * 2;
  ushort* Kh  = (ushort*)w; w += (size_t)M_TOK * KDIM * 2;
  ushort* Vt  = (ushort*)w; w += (size_t)M_TOK * KDIM * 2;
  ushort* Ob  = (ushort*)w; w += (size_t)M_TOK * KDIM * 2;

  // one fused conversion launch: x + Wq + Wk + Wv + Wo
  hipLaunchKernelGGL(cvt5_bf16_kernel, dim3(2048), dim3(256), 0, stream,
                     x, Wq, Wk, Wv, Wo, xb, Wqb, Wkb, Wvb, Wob);

  const float sl = 0.08838834764831845f * 1.4426950408889634f;  // HD^-0.5 * log2(e)

  // fused QKV: M=4096, N=6144 -> 32 x 24 tiles = 768 blocks
  hipLaunchKernelGGL((gemm2<0, 24>), dim3(768), dim3(512), 0, stream,
                     xb, Wqb, (void*)Qh, (void*)Kh, (void*)Vt, (const float*)nullptr, sl);

  hipLaunchKernelGGL(attn_kernel, dim3(512), dim3(256), 0, stream, Qh, Kh, Vt, Ob);

  // output projection: M=4096, N=2048 -> 32 x 8 tiles = 256 blocks
  hipLaunchKernelGGL((gemm2<2, 8>), dim3(256), dim3(512), 0, stream,
                     Ob, Wob, (void*)out, nullptr, nullptr, bo, 1.0f);
}